// Round 2
// baseline (663.319 us; speedup 1.0000x reference)
//
#include <hip/hip_runtime.h>

typedef _Float16 f16x8 __attribute__((ext_vector_type(8)));
typedef float    f32x4 __attribute__((ext_vector_type(4)));
typedef unsigned short u16;

#define VOC   128000
#define TOPIC 512
#define EMB   1024
#define BATCH 1024

#define BM 128
#define BN 128
#define BK 64
#define ROWB (BK * 2)   // 128 bytes per LDS row (64 f16)

// XOR swizzle: breaks the 128B-stride bank conflict on ds_read_b128 (G4/T2).
__device__ __forceinline__ int swz(int row, int kbyte) {
    return row * ROWB + (kbyte ^ ((row & 7) << 4));
}

union H2U { _Float16 h; u16 u; };

// ---------------------------------------------------------------------------
// K1: W = beta0 [V,E] @ beta_t^T [T,E]  (f16 MFMA, fp32->f16 on stage)
//     epilogue: E[v,t] = f16(exp(W[v,t])) -> EgBase + vtile*tile_stride
//               sg[t] += sum_v exp(W[v,t])
// ---------------------------------------------------------------------------
__global__ __launch_bounds__(256) void gemm1_kernel(
    const float* __restrict__ beta0, const float* __restrict__ betat,
    u16* __restrict__ EgBase, size_t tile_stride, float* __restrict__ sg)
{
    __shared__ char lds[(BM + BN) * BK * 2];   // 16KB A + 16KB B
    char* ldsA = lds;
    char* ldsB = lds + BM * BK * 2;

    const int tid  = threadIdx.x;
    const int slot = tid & 7;       // 16B slot within a 128B LDS row
    const int srow = tid >> 3;      // 0..31
    const int lane = tid & 63;
    const int wid  = tid >> 6;      // 4 waves, 2x2
    const int wr = wid >> 1, wc = wid & 1;
    const int lr = lane & 15, lk = lane >> 4;

    const int v0 = blockIdx.y * BM;   // M (vocab) tile — slow index
    const int t0 = blockIdx.x * BN;   // N (topic) tile — fast index

    f32x4 acc[4][4] = {};

    for (int kt = 0; kt < EMB / BK; ++kt) {
        const int k0 = kt * BK;
        __syncthreads();
        #pragma unroll
        for (int p = 0; p < 4; ++p) {
            const int row = p * 32 + srow;
            const float4* g = reinterpret_cast<const float4*>(
                beta0 + (size_t)(v0 + row) * EMB + k0 + slot * 8);
            float4 f0 = g[0], f1 = g[1];
            f16x8 h;
            h[0] = (_Float16)f0.x; h[1] = (_Float16)f0.y;
            h[2] = (_Float16)f0.z; h[3] = (_Float16)f0.w;
            h[4] = (_Float16)f1.x; h[5] = (_Float16)f1.y;
            h[6] = (_Float16)f1.z; h[7] = (_Float16)f1.w;
            *reinterpret_cast<f16x8*>(ldsA + swz(row, slot * 16)) = h;
        }
        #pragma unroll
        for (int p = 0; p < 4; ++p) {
            const int row = p * 32 + srow;
            const float4* g = reinterpret_cast<const float4*>(
                betat + (size_t)(t0 + row) * EMB + k0 + slot * 8);
            float4 f0 = g[0], f1 = g[1];
            f16x8 h;
            h[0] = (_Float16)f0.x; h[1] = (_Float16)f0.y;
            h[2] = (_Float16)f0.z; h[3] = (_Float16)f0.w;
            h[4] = (_Float16)f1.x; h[5] = (_Float16)f1.y;
            h[6] = (_Float16)f1.z; h[7] = (_Float16)f1.w;
            *reinterpret_cast<f16x8*>(ldsB + swz(row, slot * 16)) = h;
        }
        __syncthreads();
        #pragma unroll
        for (int ks = 0; ks < 2; ++ks) {
            f16x8 af[4], bf[4];
            #pragma unroll
            for (int m = 0; m < 4; ++m) {
                const int row = wr * 64 + m * 16 + lr;
                af[m] = *reinterpret_cast<const f16x8*>(ldsA + swz(row, ks * 64 + lk * 16));
            }
            #pragma unroll
            for (int n = 0; n < 4; ++n) {
                const int row = wc * 64 + n * 16 + lr;
                bf[n] = *reinterpret_cast<const f16x8*>(ldsB + swz(row, ks * 64 + lk * 16));
            }
            #pragma unroll
            for (int m = 0; m < 4; ++m)
                #pragma unroll
                for (int n = 0; n < 4; ++n)
                    acc[m][n] = __builtin_amdgcn_mfma_f32_16x16x32_f16(
                        af[m], bf[n], acc[m][n], 0, 0, 0);
        }
    }

    // Epilogue: exp -> LDS repack ([128][128] u16) -> vectorized E write + col sums
    __syncthreads();
    u16* ldsE = reinterpret_cast<u16*>(lds);
    #pragma unroll
    for (int m = 0; m < 4; ++m)
      #pragma unroll
      for (int n = 0; n < 4; ++n)
        #pragma unroll
        for (int r = 0; r < 4; ++r) {
            // C/D layout (m89/m91): col = lane&15, row = (lane>>4)*4 + reg
            const int row = wr * 64 + m * 16 + lk * 4 + r;
            const int col = wc * 64 + n * 16 + lr;
            H2U cv; cv.h = (_Float16)__expf(acc[m][n][r]);
            ldsE[row * BN + col] = cv.u;
        }
    __syncthreads();

    {
        const int row = tid >> 1, half = tid & 1;
        u16* dst = EgBase + (size_t)blockIdx.y * tile_stride
                 + (size_t)row * TOPIC + t0 + half * 64;
        #pragma unroll
        for (int i = 0; i < 8; ++i) {   // 8 x int4 = 64 u16 -> full half-row
            int4 vv = *reinterpret_cast<const int4*>(&ldsE[row * BN + half * 64 + i * 8]);
            *reinterpret_cast<int4*>(dst + i * 8) = vv;
        }
    }
    if (tid < BN) {
        float sum = 0.f;
        for (int r = 0; r < BM; ++r) {
            H2U cv; cv.u = ldsE[r * BN + tid];
            sum += (float)cv.h;
        }
        atomicAdd(sg + t0 + tid, sum);
    }
}

// ---------------------------------------------------------------------------
// K2: xsT[b][t] = f16( x[t][b] * 65536 / s[t] )
// ---------------------------------------------------------------------------
__global__ void xst_kernel(const float* __restrict__ x, const float* __restrict__ s,
                           u16* __restrict__ xsT)
{
    __shared__ float tile[32][33];
    const int b0 = blockIdx.x * 32, t0 = blockIdx.y * 32;
    const int tx = threadIdx.x, ty = threadIdx.y;
    tile[ty][tx] = x[(size_t)(t0 + ty) * BATCH + b0 + tx];
    __syncthreads();
    const float sc = 65536.0f / s[t0 + tx];
    H2U cv; cv.h = (_Float16)(tile[tx][ty] * sc);
    xsT[(size_t)(b0 + ty) * TOPIC + t0 + tx] = cv.u;
}

// ---------------------------------------------------------------------------
// K3-fast: out[v,b] = ( E [V,T] @ xsT^T [B,T] ) * 2^-16   (E in workspace)
// ---------------------------------------------------------------------------
__global__ __launch_bounds__(256) void gemm2_kernel(
    const u16* __restrict__ EgBase, size_t tile_stride,
    const u16* __restrict__ xsT, float* __restrict__ out)
{
    __shared__ char lds[(BM + BN) * BK * 2];
    char* ldsA = lds;
    char* ldsB = lds + BM * BK * 2;

    const int tid  = threadIdx.x;
    const int slot = tid & 7;
    const int srow = tid >> 3;
    const int lane = tid & 63;
    const int wid  = tid >> 6;
    const int wr = wid >> 1, wc = wid & 1;
    const int lr = lane & 15, lk = lane >> 4;

    const int v0 = blockIdx.y * BM;
    const int b0 = blockIdx.x * BN;
    const u16* Et = EgBase + (size_t)blockIdx.y * tile_stride;

    f32x4 acc[4][4] = {};

    for (int kt = 0; kt < TOPIC / BK; ++kt) {
        const int k0 = kt * BK;
        __syncthreads();
        #pragma unroll
        for (int p = 0; p < 4; ++p) {
            const int row = p * 32 + srow;
            int4 vv = *reinterpret_cast<const int4*>(
                Et + (size_t)row * TOPIC + k0 + slot * 8);
            *reinterpret_cast<int4*>(ldsA + swz(row, slot * 16)) = vv;
        }
        #pragma unroll
        for (int p = 0; p < 4; ++p) {
            const int row = p * 32 + srow;
            int4 vv = *reinterpret_cast<const int4*>(
                xsT + (size_t)(b0 + row) * TOPIC + k0 + slot * 8);
            *reinterpret_cast<int4*>(ldsB + swz(row, slot * 16)) = vv;
        }
        __syncthreads();
        #pragma unroll
        for (int ks = 0; ks < 2; ++ks) {
            f16x8 af[4], bf[4];
            #pragma unroll
            for (int m = 0; m < 4; ++m) {
                const int row = wr * 64 + m * 16 + lr;
                af[m] = *reinterpret_cast<const f16x8*>(ldsA + swz(row, ks * 64 + lk * 16));
            }
            #pragma unroll
            for (int n = 0; n < 4; ++n) {
                const int row = wc * 64 + n * 16 + lr;
                bf[n] = *reinterpret_cast<const f16x8*>(ldsB + swz(row, ks * 64 + lk * 16));
            }
            #pragma unroll
            for (int m = 0; m < 4; ++m)
                #pragma unroll
                for (int n = 0; n < 4; ++n)
                    acc[m][n] = __builtin_amdgcn_mfma_f32_16x16x32_f16(
                        af[m], bf[n], acc[m][n], 0, 0, 0);
        }
    }

    #pragma unroll
    for (int m = 0; m < 4; ++m)
      #pragma unroll
      for (int n = 0; n < 4; ++n)
        #pragma unroll
        for (int r = 0; r < 4; ++r) {
            const int row = wr * 64 + m * 16 + lk * 4 + r;
            const int col = wc * 64 + n * 16 + lr;
            out[(size_t)(v0 + row) * BATCH + b0 + col] = acc[m][n][r] * 0x1p-16f;
        }
}

// ---------------------------------------------------------------------------
// K3-fallback: E-tiles live inside d_out's own v-tile regions (no big ws).
// Block = one 128-row v-tile. Loads its E-tile fully into registers, fences,
// then computes out[128,1024] in 8 chunks of 128 cols and overwrites region.
// ---------------------------------------------------------------------------
__global__ __launch_bounds__(512) void gemm2_fused_kernel(
    const u16* __restrict__ EgBase,   // == (u16*)out
    const u16* __restrict__ xsT, float* __restrict__ out)
{
    __shared__ char ldsB[BN * BK * 2];   // 16KB

    const int tid  = threadIdx.x;
    const int lane = tid & 63;
    const int wid  = tid >> 6;          // 8 waves: 2 (rows) x 4 (cols)
    const int wr = wid >> 2, wc = wid & 3;
    const int lr = lane & 15, lk = lane >> 4;

    const size_t tile = blockIdx.x;
    const u16* Et = EgBase + tile * (size_t)(BM * BATCH * 2);  // 262144 u16/region

    // A-fragments for the whole K=512: 4 m-frags x 16 k-blocks of 32
    f16x8 af[4][16];
    #pragma unroll
    for (int m = 0; m < 4; ++m) {
        const int row = wr * 64 + m * 16 + lr;
        #pragma unroll
        for (int kb = 0; kb < 16; ++kb)
            af[m][kb] = *reinterpret_cast<const f16x8*>(
                Et + (size_t)row * TOPIC + kb * 32 + lk * 8);
    }
    asm volatile("s_waitcnt vmcnt(0)" ::: "memory");  // E fully read...
    __syncthreads();                                  // ...before ANY out write

    for (int bc = 0; bc < 8; ++bc) {        // 128-col batch chunks
        f32x4 acc[4][2] = {};
        #pragma unroll
        for (int ks = 0; ks < 8; ++ks) {    // 64-wide k-slices
            __syncthreads();
            {   // stage xsT chunk [128][64] -> ldsB (swizzled)
                const int srow = tid >> 2;
                const int slot = (tid & 3) * 2;
                const u16* g = xsT + (size_t)(bc * 128 + srow) * TOPIC + ks * 64 + slot * 8;
                int4 v0 = *reinterpret_cast<const int4*>(g);
                int4 v1 = *reinterpret_cast<const int4*>(g + 8);
                *reinterpret_cast<int4*>(ldsB + swz(srow, slot * 16)) = v0;
                *reinterpret_cast<int4*>(ldsB + swz(srow, (slot + 1) * 16)) = v1;
            }
            __syncthreads();
            #pragma unroll
            for (int kk = 0; kk < 2; ++kk) {
                f16x8 bf[2];
                #pragma unroll
                for (int n = 0; n < 2; ++n) {
                    const int row = wc * 32 + n * 16 + lr;
                    bf[n] = *reinterpret_cast<const f16x8*>(ldsB + swz(row, kk * 64 + lk * 16));
                }
                #pragma unroll
                for (int m = 0; m < 4; ++m)
                    #pragma unroll
                    for (int n = 0; n < 2; ++n)
                        acc[m][n] = __builtin_amdgcn_mfma_f32_16x16x32_f16(
                            af[m][ks * 2 + kk], bf[n], acc[m][n], 0, 0, 0);
            }
        }
        #pragma unroll
        for (int m = 0; m < 4; ++m)
          #pragma unroll
          for (int n = 0; n < 2; ++n)
            #pragma unroll
            for (int r = 0; r < 4; ++r) {
                const int row = wr * 64 + m * 16 + lk * 4 + r;
                const int col = wc * 32 + n * 16 + lr;
                out[(tile * BM + row) * BATCH + bc * 128 + col] = acc[m][n][r] * 0x1p-16f;
            }
    }
}

// ---------------------------------------------------------------------------
extern "C" void kernel_launch(void* const* d_in, const int* in_sizes, int n_in,
                              void* d_out, int out_size, void* d_ws, size_t ws_size,
                              hipStream_t stream)
{
    const float* x     = (const float*)d_in[0];
    const float* beta0 = (const float*)d_in[1];
    const float* betat = (const float*)d_in[2];
    float* out = (float*)d_out;

    // ws layout: s[512] f32 @ 0 | xsT [1024][512] f16 @ 4KB | (fast only) E @ 2MB
    const size_t E_OFF    = 2u * 1024u * 1024u;
    const size_t need_big = E_OFF + (size_t)VOC * TOPIC * 2;    // ~127 MiB
    const size_t need_min = 4096 + (size_t)BATCH * TOPIC * 2;   // ~1 MiB
    if (ws_size < need_min) return;

    float* s_g = (float*)d_ws;
    u16*   xsT = (u16*)((char*)d_ws + 4096);

    hipMemsetAsync(d_ws, 0, 2048, stream);  // zero s[t] accumulators

    if (ws_size >= need_big) {
        // -------- fast path: E in workspace --------
        u16* Eg = (u16*)((char*)d_ws + E_OFF);
        const size_t tstride = (size_t)BM * TOPIC;   // 65536 u16 per v-tile

        dim3 g1(TOPIC / BN, VOC / BM);
        gemm1_kernel<<<g1, 256, 0, stream>>>(beta0, betat, Eg, tstride, s_g);

        dim3 gp(BATCH / 32, TOPIC / 32);
        xst_kernel<<<gp, dim3(32, 32), 0, stream>>>(x, s_g, xsT);

        dim3 g2(BATCH / BN, VOC / BM);
        gemm2_kernel<<<g2, 256, 0, stream>>>(Eg, tstride, xsT, out);
    } else {
        // -------- fallback: E-tiles inside d_out regions --------
        u16* Eg = (u16*)d_out;
        const size_t tstride = (size_t)BM * BATCH * 2;  // 262144 u16 per region

        dim3 g1(TOPIC / BN, VOC / BM);
        gemm1_kernel<<<g1, 256, 0, stream>>>(beta0, betat, Eg, tstride, s_g);

        dim3 gp(BATCH / 32, TOPIC / 32);
        xst_kernel<<<gp, dim3(32, 32), 0, stream>>>(x, s_g, xsT);

        gemm2_fused_kernel<<<dim3(VOC / BM), 512, 0, stream>>>(Eg, xsT, out);
    }
}

// Round 3
// 630.879 us; speedup vs baseline: 1.0514x; 1.0514x over previous
//
#include <hip/hip_runtime.h>

typedef _Float16 f16x8 __attribute__((ext_vector_type(8)));
typedef float    f32x4 __attribute__((ext_vector_type(4)));
typedef unsigned short u16;

#define VOC   128000
#define TOPIC 512
#define EMB   1024
#define BATCH 1024

#define BM 128
#define BN 128
#define BK 64
#define ROWB (BK * 2)   // 128 bytes per LDS row (64 f16)

// XOR swizzle: breaks the 128B-stride bank conflict on ds_read_b128 (G4/T2).
__device__ __forceinline__ int swz(int row, int kbyte) {
    return row * ROWB + (kbyte ^ ((row & 7) << 4));
}

union H2U { _Float16 h; u16 u; };

// Bijective XCD-chunked block swizzle (T1, m204): consecutive logical blocks
// (which share an operand panel) land on the SAME XCD. Requires nwg % 8 == 0.
__device__ __forceinline__ int xcd_swz(int bid, int nwg) {
    return (bid & 7) * (nwg >> 3) + (bid >> 3);
}

// ---------------------------------------------------------------------------
// K1: W = beta0 [V,E] @ beta_t^T [T,E]  (f16 MFMA, fp32->f16 on reg-stage,
//     T14 async-split: next tile's loads issued before the compute barrier)
//     epilogue: E[v,t] = f16(exp(W[v,t])); sg[t] += col-sums
// ---------------------------------------------------------------------------
__global__ __launch_bounds__(256) void gemm1_kernel(
    const float* __restrict__ beta0, const float* __restrict__ betat,
    u16* __restrict__ EgBase, size_t tile_stride, float* __restrict__ sg)
{
    __shared__ char lds[(BM + BN) * BK * 2];   // 16KB A + 16KB B
    char* ldsA = lds;
    char* ldsB = lds + BM * BK * 2;

    const int tid  = threadIdx.x;
    const int slot = tid & 7;       // 16B slot within a 128B LDS row
    const int srow = tid >> 3;      // 0..31
    const int lane = tid & 63;
    const int wid  = tid >> 6;      // 4 waves, 2x2
    const int wr = wid >> 1, wc = wid & 1;
    const int lr = lane & 15, lk = lane >> 4;

    const int bid = xcd_swz(blockIdx.x, gridDim.x);
    const int t0 = (bid & 3) * BN;    // 4 t-tiles/panel -> co-XCD
    const int v0 = (bid >> 2) * BM;

    f32x4 acc[4][4] = {};
    float4 rA0[4], rA1[4], rB0[4], rB1[4];

    auto load_tiles = [&](int kt) {
        const int k0 = kt * BK;
        #pragma unroll
        for (int p = 0; p < 4; ++p) {
            const float4* gA = reinterpret_cast<const float4*>(
                beta0 + (size_t)(v0 + p * 32 + srow) * EMB + k0 + slot * 8);
            rA0[p] = gA[0]; rA1[p] = gA[1];
            const float4* gB = reinterpret_cast<const float4*>(
                betat + (size_t)(t0 + p * 32 + srow) * EMB + k0 + slot * 8);
            rB0[p] = gB[0]; rB1[p] = gB[1];
        }
    };

    load_tiles(0);

    for (int kt = 0; kt < EMB / BK; ++kt) {
        __syncthreads();   // previous compute done; LDS writable
        #pragma unroll
        for (int p = 0; p < 4; ++p) {
            const int row = p * 32 + srow;
            f16x8 h;
            h[0] = (_Float16)rA0[p].x; h[1] = (_Float16)rA0[p].y;
            h[2] = (_Float16)rA0[p].z; h[3] = (_Float16)rA0[p].w;
            h[4] = (_Float16)rA1[p].x; h[5] = (_Float16)rA1[p].y;
            h[6] = (_Float16)rA1[p].z; h[7] = (_Float16)rA1[p].w;
            *reinterpret_cast<f16x8*>(ldsA + swz(row, slot * 16)) = h;
            f16x8 g;
            g[0] = (_Float16)rB0[p].x; g[1] = (_Float16)rB0[p].y;
            g[2] = (_Float16)rB0[p].z; g[3] = (_Float16)rB0[p].w;
            g[4] = (_Float16)rB1[p].x; g[5] = (_Float16)rB1[p].y;
            g[6] = (_Float16)rB1[p].z; g[7] = (_Float16)rB1[p].w;
            *reinterpret_cast<f16x8*>(ldsB + swz(row, slot * 16)) = g;
        }
        if (kt + 1 < EMB / BK) load_tiles(kt + 1);   // T14: issue early, use late
        __syncthreads();
        #pragma unroll
        for (int ks = 0; ks < 2; ++ks) {
            f16x8 af[4], bf[4];
            #pragma unroll
            for (int m = 0; m < 4; ++m) {
                const int row = wr * 64 + m * 16 + lr;
                af[m] = *reinterpret_cast<const f16x8*>(ldsA + swz(row, ks * 64 + lk * 16));
            }
            #pragma unroll
            for (int n = 0; n < 4; ++n) {
                const int row = wc * 64 + n * 16 + lr;
                bf[n] = *reinterpret_cast<const f16x8*>(ldsB + swz(row, ks * 64 + lk * 16));
            }
            #pragma unroll
            for (int m = 0; m < 4; ++m)
                #pragma unroll
                for (int n = 0; n < 4; ++n)
                    acc[m][n] = __builtin_amdgcn_mfma_f32_16x16x32_f16(
                        af[m], bf[n], acc[m][n], 0, 0, 0);
        }
    }

    // Epilogue: exp -> LDS repack ([128][128] u16) -> vectorized E write + col sums
    __syncthreads();
    u16* ldsE = reinterpret_cast<u16*>(lds);
    #pragma unroll
    for (int m = 0; m < 4; ++m)
      #pragma unroll
      for (int n = 0; n < 4; ++n)
        #pragma unroll
        for (int r = 0; r < 4; ++r) {
            // C/D layout (m89/m91): col = lane&15, row = (lane>>4)*4 + reg
            const int row = wr * 64 + m * 16 + lk * 4 + r;
            const int col = wc * 64 + n * 16 + lr;
            H2U cv; cv.h = (_Float16)__expf(acc[m][n][r]);
            ldsE[row * BN + col] = cv.u;
        }
    __syncthreads();

    {
        const int row = tid >> 1, half = tid & 1;
        u16* dst = EgBase + (size_t)(v0 / BM) * tile_stride
                 + (size_t)row * TOPIC + t0 + half * 64;
        #pragma unroll
        for (int i = 0; i < 8; ++i) {
            int4 vv = *reinterpret_cast<const int4*>(&ldsE[row * BN + half * 64 + i * 8]);
            *reinterpret_cast<int4*>(dst + i * 8) = vv;
        }
    }
    if (tid < BN) {
        float sum = 0.f;
        for (int r = 0; r < BM; ++r) {
            H2U cv; cv.u = ldsE[r * BN + tid];
            sum += (float)cv.h;
        }
        atomicAdd(sg + t0 + tid, sum);
    }
}

// ---------------------------------------------------------------------------
// K2: xsT[b][t] = f16( x[t][b] * 65536 / s[t] )
// ---------------------------------------------------------------------------
__global__ void xst_kernel(const float* __restrict__ x, const float* __restrict__ s,
                           u16* __restrict__ xsT)
{
    __shared__ float tile[32][33];
    const int b0 = blockIdx.x * 32, t0 = blockIdx.y * 32;
    const int tx = threadIdx.x, ty = threadIdx.y;
    tile[ty][tx] = x[(size_t)(t0 + ty) * BATCH + b0 + tx];
    __syncthreads();
    const float sc = 65536.0f / s[t0 + tx];
    H2U cv; cv.h = (_Float16)(tile[tx][ty] * sc);
    xsT[(size_t)(b0 + ty) * TOPIC + t0 + tx] = cv.u;
}

// ---------------------------------------------------------------------------
// K3: out[v,b] = ( E [V,T] @ xsT^T [B,T] ) * 2^-16
// Staging via global_load_lds width=16: linear LDS dest + pre-swizzled global
// source (m173). Source chunk (lane&7)^(lane>>3) is the same XOR involution
// the ds_read side applies, so reads land on the right data.
// ---------------------------------------------------------------------------
__global__ __launch_bounds__(256) void gemm2_kernel(
    const u16* __restrict__ EgBase, size_t tile_stride,
    const u16* __restrict__ xsT, float* __restrict__ out)
{
    __shared__ char lds[(BM + BN) * BK * 2];
    char* ldsA = lds;
    char* ldsB = lds + BM * BK * 2;

    const int tid  = threadIdx.x;
    const int lane = tid & 63;
    const int w    = tid >> 6;
    const int wr = w >> 1, wc = w & 1;
    const int lr = lane & 15, lk = lane >> 4;

    const int bid = xcd_swz(blockIdx.x, gridDim.x);
    const int b0 = (bid & 7) * BN;    // 8 b-tiles/E-panel -> co-XCD
    const int v0 = (bid >> 3) * BM;

    const u16* Et = EgBase + (size_t)(v0 / BM) * tile_stride;

    const int srow8  = lane >> 3;                 // row within 8-row group
    const int schunk = ((lane & 7) ^ srow8) * 8;  // pre-swizzled 16B chunk (u16 units)

    f32x4 acc[4][4] = {};

    for (int kt = 0; kt < TOPIC / BK; ++kt) {
        const int k0 = kt * BK;
        __syncthreads();
        #pragma unroll
        for (int p = 0; p < 4; ++p) {
            const int rbase = p * 32 + w * 8;     // wave-uniform 8-row group
            const u16* gA = Et + (size_t)(rbase + srow8) * TOPIC + k0 + schunk;
            __builtin_amdgcn_global_load_lds(
                (const __attribute__((address_space(1))) unsigned int*)gA,
                (__attribute__((address_space(3))) unsigned int*)(ldsA + rbase * ROWB),
                16, 0, 0);
            const u16* gB = xsT + (size_t)(b0 + rbase + srow8) * TOPIC + k0 + schunk;
            __builtin_amdgcn_global_load_lds(
                (const __attribute__((address_space(1))) unsigned int*)gB,
                (__attribute__((address_space(3))) unsigned int*)(ldsB + rbase * ROWB),
                16, 0, 0);
        }
        __syncthreads();
        #pragma unroll
        for (int ks = 0; ks < 2; ++ks) {
            f16x8 af[4], bf[4];
            #pragma unroll
            for (int m = 0; m < 4; ++m) {
                const int row = wr * 64 + m * 16 + lr;
                af[m] = *reinterpret_cast<const f16x8*>(ldsA + swz(row, ks * 64 + lk * 16));
            }
            #pragma unroll
            for (int n = 0; n < 4; ++n) {
                const int row = wc * 64 + n * 16 + lr;
                bf[n] = *reinterpret_cast<const f16x8*>(ldsB + swz(row, ks * 64 + lk * 16));
            }
            #pragma unroll
            for (int m = 0; m < 4; ++m)
                #pragma unroll
                for (int n = 0; n < 4; ++n)
                    acc[m][n] = __builtin_amdgcn_mfma_f32_16x16x32_f16(
                        af[m], bf[n], acc[m][n], 0, 0, 0);
        }
    }

    #pragma unroll
    for (int m = 0; m < 4; ++m)
      #pragma unroll
      for (int n = 0; n < 4; ++n)
        #pragma unroll
        for (int r = 0; r < 4; ++r) {
            const int row = wr * 64 + m * 16 + lk * 4 + r;
            const int col = wc * 64 + n * 16 + lr;
            out[(size_t)(v0 + row) * BATCH + b0 + col] = acc[m][n][r] * 0x1p-16f;
        }
}

// ---------------------------------------------------------------------------
// K3-fallback (small ws): E-tiles live inside d_out's own v-tile regions.
// ---------------------------------------------------------------------------
__global__ __launch_bounds__(512) void gemm2_fused_kernel(
    const u16* __restrict__ EgBase,   // == (u16*)out
    const u16* __restrict__ xsT, float* __restrict__ out)
{
    __shared__ char ldsB[BN * BK * 2];   // 16KB

    const int tid  = threadIdx.x;
    const int lane = tid & 63;
    const int wid  = tid >> 6;          // 8 waves: 2 (rows) x 4 (cols)
    const int wr = wid >> 2, wc = wid & 3;
    const int lr = lane & 15, lk = lane >> 4;

    const size_t tile = blockIdx.x;
    const u16* Et = EgBase + tile * (size_t)(BM * BATCH * 2);

    f16x8 af[4][16];
    #pragma unroll
    for (int m = 0; m < 4; ++m) {
        const int row = wr * 64 + m * 16 + lr;
        #pragma unroll
        for (int kb = 0; kb < 16; ++kb)
            af[m][kb] = *reinterpret_cast<const f16x8*>(
                Et + (size_t)row * TOPIC + kb * 32 + lk * 8);
    }
    asm volatile("s_waitcnt vmcnt(0)" ::: "memory");  // E fully read...
    __syncthreads();                                  // ...before ANY out write

    for (int bc = 0; bc < 8; ++bc) {
        f32x4 acc[4][2] = {};
        #pragma unroll
        for (int ks = 0; ks < 8; ++ks) {
            __syncthreads();
            {
                const int srow = tid >> 2;
                const int slot = (tid & 3) * 2;
                const u16* g = xsT + (size_t)(bc * 128 + srow) * TOPIC + ks * 64 + slot * 8;
                int4 v0 = *reinterpret_cast<const int4*>(g);
                int4 v1 = *reinterpret_cast<const int4*>(g + 8);
                *reinterpret_cast<int4*>(ldsB + swz(srow, slot * 16)) = v0;
                *reinterpret_cast<int4*>(ldsB + swz(srow, (slot + 1) * 16)) = v1;
            }
            __syncthreads();
            #pragma unroll
            for (int kk = 0; kk < 2; ++kk) {
                f16x8 bf[2];
                #pragma unroll
                for (int n = 0; n < 2; ++n) {
                    const int row = wc * 32 + n * 16 + lr;
                    bf[n] = *reinterpret_cast<const f16x8*>(ldsB + swz(row, kk * 64 + lk * 16));
                }
                #pragma unroll
                for (int m = 0; m < 4; ++m)
                    #pragma unroll
                    for (int n = 0; n < 2; ++n)
                        acc[m][n] = __builtin_amdgcn_mfma_f32_16x16x32_f16(
                            af[m][ks * 2 + kk], bf[n], acc[m][n], 0, 0, 0);
            }
        }
        #pragma unroll
        for (int m = 0; m < 4; ++m)
          #pragma unroll
          for (int n = 0; n < 2; ++n)
            #pragma unroll
            for (int r = 0; r < 4; ++r) {
                const int row = wr * 64 + m * 16 + lk * 4 + r;
                const int col = wc * 32 + n * 16 + lr;
                out[(tile * BM + row) * BATCH + bc * 128 + col] = acc[m][n][r] * 0x1p-16f;
            }
    }
}

// ---------------------------------------------------------------------------
extern "C" void kernel_launch(void* const* d_in, const int* in_sizes, int n_in,
                              void* d_out, int out_size, void* d_ws, size_t ws_size,
                              hipStream_t stream)
{
    const float* x     = (const float*)d_in[0];
    const float* beta0 = (const float*)d_in[1];
    const float* betat = (const float*)d_in[2];
    float* out = (float*)d_out;

    const size_t E_OFF    = 2u * 1024u * 1024u;
    const size_t need_big = E_OFF + (size_t)VOC * TOPIC * 2;    // ~127 MiB
    const size_t need_min = 4096 + (size_t)BATCH * TOPIC * 2;   // ~1 MiB
    if (ws_size < need_min) return;

    float* s_g = (float*)d_ws;
    u16*   xsT = (u16*)((char*)d_ws + 4096);

    hipMemsetAsync(d_ws, 0, 2048, stream);  // zero s[t] accumulators

    if (ws_size >= need_big) {
        // -------- fast path: E in workspace --------
        u16* Eg = (u16*)((char*)d_ws + E_OFF);
        const size_t tstride = (size_t)BM * TOPIC;

        gemm1_kernel<<<dim3((TOPIC / BN) * (VOC / BM)), 256, 0, stream>>>(
            beta0, betat, Eg, tstride, s_g);

        dim3 gp(BATCH / 32, TOPIC / 32);
        xst_kernel<<<gp, dim3(32, 32), 0, stream>>>(x, s_g, xsT);

        gemm2_kernel<<<dim3((BATCH / BN) * (VOC / BM)), 256, 0, stream>>>(
            Eg, tstride, xsT, out);
    } else {
        // -------- fallback: E-tiles inside d_out regions --------
        u16* Eg = (u16*)d_out;
        const size_t tstride = (size_t)BM * BATCH * 2;

        gemm1_kernel<<<dim3((TOPIC / BN) * (VOC / BM)), 256, 0, stream>>>(
            beta0, betat, Eg, tstride, s_g);

        dim3 gp(BATCH / 32, TOPIC / 32);
        xst_kernel<<<gp, dim3(32, 32), 0, stream>>>(x, s_g, xsT);

        gemm2_fused_kernel<<<dim3(VOC / BM), 512, 0, stream>>>(Eg, xsT, out);
    }
}

// Round 4
// 581.975 us; speedup vs baseline: 1.1398x; 1.0840x over previous
//
#include <hip/hip_runtime.h>

typedef _Float16 f16x8 __attribute__((ext_vector_type(8)));
typedef float    f32x4 __attribute__((ext_vector_type(4)));
typedef unsigned short u16;

#define VOC   128000
#define TOPIC 512
#define EMB   1024
#define BATCH 1024
#define ROWB  128   // LDS row = 64 f16 = 128 B

// XOR swizzle vs 128B-stride bank conflicts (G4/T2)
__device__ __forceinline__ int swz(int row, int kbyte) {
    return row * ROWB + (kbyte ^ ((row & 7) << 4));
}
// Bijective XCD-chunked swizzle (T1/m204); requires nwg % 8 == 0.
__device__ __forceinline__ int xcd_swz(int bid, int nwg) {
    return (bid & 7) * (nwg >> 3) + (bid >> 3);
}
union H2U { _Float16 h; u16 u; };

// ---------------------------------------------------------------------------
// K0: betat f32 -> f16 (into the ws MB that xst later overwrites with xsT)
// ---------------------------------------------------------------------------
__global__ void cvt_betat_kernel(const float* __restrict__ betat, u16* __restrict__ bt16) {
    const size_t g = (size_t)blockIdx.x * 256 + threadIdx.x;   // 65536 threads x 8 elems
    const float4* src = reinterpret_cast<const float4*>(betat) + g * 2;
    float4 a = src[0], b = src[1];
    f16x8 h;
    h[0]=(_Float16)a.x; h[1]=(_Float16)a.y; h[2]=(_Float16)a.z; h[3]=(_Float16)a.w;
    h[4]=(_Float16)b.x; h[5]=(_Float16)b.y; h[6]=(_Float16)b.z; h[7]=(_Float16)b.w;
    *(reinterpret_cast<f16x8*>(bt16) + g) = h;
}

// ---------------------------------------------------------------------------
// K1: W = beta0 [V,E] @ betat16^T ; E[v,t]=f16(exp(W)) -> Eg (strided rows);
//     sg[t] += col sums.  8 waves, 128x256 tile, BK=64.
//     A: f32 reg-stage + cvt (T14 early-issue). B: global_load_lds (pre-swz src).
// ---------------------------------------------------------------------------
__global__ __launch_bounds__(512, 2) void gemm1_kernel(
    const float* __restrict__ beta0, const u16* __restrict__ bt16,
    u16* __restrict__ Eg, size_t TSTR, int RSTR, float* __restrict__ sg)
{
    __shared__ char lds[49152];
    char* ldsA = lds;            // 16 KB: 128 rows x 128 B
    char* ldsB = lds + 16384;    // 32 KB: 256 rows x 128 B

    const int tid  = threadIdx.x;
    const int lane = tid & 63;
    const int wid  = tid >> 6;            // 8 waves: 2 (v) x 4 (t)
    const int wr = wid >> 2, wc = wid & 3;
    const int lr = lane & 15, lk = lane >> 4;
    const int srow8  = lane >> 3;
    const int schunk = ((lane & 7) ^ srow8) * 8;   // pre-swizzled 16B chunk (u16)

    const int bid  = xcd_swz(blockIdx.x, gridDim.x);
    const int t0   = (bid & 1) * 256;     // pair of t-halves co-XCD
    const int tile = bid >> 1;
    const int v0   = tile * 128;

    const int arow = tid >> 2;            // A-stage: row 0..127
    const int asp  = (tid & 3) * 2;       // slot pair

    f32x4 acc[4][4] = {};
    float4 rA[4];

    auto loadA = [&](int kt) {
        const float4* g = reinterpret_cast<const float4*>(
            beta0 + (size_t)(v0 + arow) * EMB + kt * 64 + asp * 8);
        rA[0] = g[0]; rA[1] = g[1]; rA[2] = g[2]; rA[3] = g[3];
    };

    loadA(0);

    for (int kt = 0; kt < EMB / 64; ++kt) {
        __syncthreads();
        // B: 4 x global_load_lds rounds (rows p*64 + wid*8 + srow8)
        const u16* bsrc = bt16 + (size_t)(t0 + wid * 8 + srow8) * EMB + kt * 64 + schunk;
        #pragma unroll
        for (int p = 0; p < 4; ++p) {
            __builtin_amdgcn_global_load_lds(
                (const __attribute__((address_space(1))) unsigned int*)(bsrc + (size_t)p * 64 * EMB),
                (__attribute__((address_space(3))) unsigned int*)(ldsB + (p * 64 + wid * 8) * ROWB),
                16, 0, 0);
        }
        // A: cvt from prefetched regs -> swizzled ds_write
        {
            f16x8 h;
            h[0]=(_Float16)rA[0].x; h[1]=(_Float16)rA[0].y; h[2]=(_Float16)rA[0].z; h[3]=(_Float16)rA[0].w;
            h[4]=(_Float16)rA[1].x; h[5]=(_Float16)rA[1].y; h[6]=(_Float16)rA[1].z; h[7]=(_Float16)rA[1].w;
            *reinterpret_cast<f16x8*>(ldsA + swz(arow, asp * 16)) = h;
            f16x8 h2;
            h2[0]=(_Float16)rA[2].x; h2[1]=(_Float16)rA[2].y; h2[2]=(_Float16)rA[2].z; h2[3]=(_Float16)rA[2].w;
            h2[4]=(_Float16)rA[3].x; h2[5]=(_Float16)rA[3].y; h2[6]=(_Float16)rA[3].z; h2[7]=(_Float16)rA[3].w;
            *reinterpret_cast<f16x8*>(ldsA + swz(arow, (asp + 1) * 16)) = h2;
        }
        if (kt + 1 < EMB / 64) loadA(kt + 1);   // T14: issue early, use next iter
        __syncthreads();
        #pragma unroll
        for (int ks = 0; ks < 2; ++ks) {
            f16x8 af[4], bf[4];
            #pragma unroll
            for (int m = 0; m < 4; ++m)
                af[m] = *reinterpret_cast<const f16x8*>(ldsA + swz(wr * 64 + m * 16 + lr, ks * 64 + lk * 16));
            #pragma unroll
            for (int n = 0; n < 4; ++n)
                bf[n] = *reinterpret_cast<const f16x8*>(ldsB + swz(wc * 64 + n * 16 + lr, ks * 64 + lk * 16));
            #pragma unroll
            for (int m = 0; m < 4; ++m)
                #pragma unroll
                for (int n = 0; n < 4; ++n)
                    acc[m][n] = __builtin_amdgcn_mfma_f32_16x16x32_f16(
                        af[m], bf[n], acc[m][n], 0, 0, 0);
        }
    }

    // Epilogue: 2 chunks of 64 rows; exp -> LDS repack (stride 264) -> E write + colsum
    __syncthreads();
    u16* ldsE = reinterpret_cast<u16*>(lds);   // 64 x 264 u16 = 33.8 KB
    float csum = 0.f;
    #pragma unroll
    for (int c = 0; c < 2; ++c) {
        if (wr == c) {
            #pragma unroll
            for (int m = 0; m < 4; ++m)
              #pragma unroll
              for (int n = 0; n < 4; ++n)
                #pragma unroll
                for (int r = 0; r < 4; ++r) {
                    // C/D layout (m89/m91): col = lane&15, row = (lane>>4)*4 + reg
                    const int row = m * 16 + lk * 4 + r;        // 0..63
                    const int col = wc * 64 + n * 16 + lr;      // 0..255
                    H2U cv; cv.h = (_Float16)__expf(acc[m][n][r]);
                    ldsE[row * 264 + col] = cv.u;
                }
        }
        __syncthreads();
        {   // coalesced E write: 64 rows x 512 B
            const int row8 = tid >> 3, seg = tid & 7;
            const int4* srcp = reinterpret_cast<const int4*>(&ldsE[row8 * 264 + seg * 32]);
            u16* dst = Eg + tile * TSTR + (size_t)(c * 64 + row8) * RSTR + t0 + seg * 32;
            int4 v0v = srcp[0], v1v = srcp[1], v2v = srcp[2], v3v = srcp[3];
            int4* dp = reinterpret_cast<int4*>(dst);
            dp[0] = v0v; dp[1] = v1v; dp[2] = v2v; dp[3] = v3v;
        }
        if (tid < 256) {
            float s = 0.f;
            for (int r = 0; r < 64; ++r) { H2U cv; cv.u = ldsE[r * 264 + tid]; s += (float)cv.h; }
            csum += s;
        }
        __syncthreads();
    }
    if (tid < 256) atomicAdd(sg + t0 + tid, csum);
}

// ---------------------------------------------------------------------------
// K2: xsT[b][t] = f16( x[t][b] * 65536 / s[t] )  (overwrites betat16 MB)
// ---------------------------------------------------------------------------
__global__ void xst_kernel(const float* __restrict__ x, const float* __restrict__ s,
                           u16* __restrict__ xsT)
{
    __shared__ float tile[32][33];
    const int b0 = blockIdx.x * 32, t0 = blockIdx.y * 32;
    const int tx = threadIdx.x, ty = threadIdx.y;
    tile[ty][tx] = x[(size_t)(t0 + ty) * BATCH + b0 + tx];
    __syncthreads();
    const float sc = 65536.0f / s[t0 + tx];
    H2U cv; cv.h = (_Float16)(tile[tx][ty] * sc);
    xsT[(size_t)(b0 + ty) * TOPIC + t0 + tx] = cv.u;
}

// ---------------------------------------------------------------------------
// K3a: out[v, b0..] = (E @ xsT^T) * 2^-16 ; 8 waves, 128x256 tile, BK=64,
//      both operands via global_load_lds (pre-swizzled source).
//      Covers cols >= 256 in fallback (never touches E bytes), all cols if E in ws.
// ---------------------------------------------------------------------------
__global__ __launch_bounds__(512, 2) void gemm2a_kernel(
    const u16* __restrict__ Eg, size_t TSTR, int RSTR,
    const u16* __restrict__ xsT, float* __restrict__ out, int c0, int nch)
{
    __shared__ char lds[49152];
    char* ldsA = lds;            // 16 KB
    char* ldsB = lds + 16384;    // 32 KB

    const int tid  = threadIdx.x;
    const int lane = tid & 63;
    const int wid  = tid >> 6;
    const int wr = wid >> 2, wc = wid & 3;
    const int lr = lane & 15, lk = lane >> 4;
    const int srow8  = lane >> 3;
    const int schunk = ((lane & 7) ^ srow8) * 8;

    const int bid   = xcd_swz(blockIdx.x, gridDim.x);
    const int tile  = bid / nch;
    const int chunk = bid % nch;
    const int b0    = c0 + chunk * 256;
    const int v0    = tile * 128;
    const u16* Et   = Eg + tile * TSTR;

    f32x4 acc[4][4] = {};

    for (int kt = 0; kt < TOPIC / 64; ++kt) {
        const int k0 = kt * 64;
        __syncthreads();
        #pragma unroll
        for (int p = 0; p < 2; ++p) {   // A: 128 rows of E
            const int rbase = p * 64 + wid * 8;
            __builtin_amdgcn_global_load_lds(
                (const __attribute__((address_space(1))) unsigned int*)
                    (Et + (size_t)(rbase + srow8) * RSTR + k0 + schunk),
                (__attribute__((address_space(3))) unsigned int*)(ldsA + rbase * ROWB),
                16, 0, 0);
        }
        #pragma unroll
        for (int p = 0; p < 4; ++p) {   // B: 256 rows of xsT
            const int rbase = p * 64 + wid * 8;
            __builtin_amdgcn_global_load_lds(
                (const __attribute__((address_space(1))) unsigned int*)
                    (xsT + (size_t)(b0 + rbase + srow8) * TOPIC + k0 + schunk),
                (__attribute__((address_space(3))) unsigned int*)(ldsB + rbase * ROWB),
                16, 0, 0);
        }
        __syncthreads();
        #pragma unroll
        for (int ks = 0; ks < 2; ++ks) {
            f16x8 af[4], bf[4];
            #pragma unroll
            for (int m = 0; m < 4; ++m)
                af[m] = *reinterpret_cast<const f16x8*>(ldsA + swz(wr * 64 + m * 16 + lr, ks * 64 + lk * 16));
            #pragma unroll
            for (int n = 0; n < 4; ++n)
                bf[n] = *reinterpret_cast<const f16x8*>(ldsB + swz(wc * 64 + n * 16 + lr, ks * 64 + lk * 16));
            #pragma unroll
            for (int m = 0; m < 4; ++m)
                #pragma unroll
                for (int n = 0; n < 4; ++n)
                    acc[m][n] = __builtin_amdgcn_mfma_f32_16x16x32_f16(
                        af[m], bf[n], acc[m][n], 0, 0, 0);
        }
    }

    #pragma unroll
    for (int m = 0; m < 4; ++m)
      #pragma unroll
      for (int n = 0; n < 4; ++n)
        #pragma unroll
        for (int r = 0; r < 4; ++r) {
            const int row = wr * 64 + m * 16 + lk * 4 + r;
            const int col = wc * 64 + n * 16 + lr;
            out[(size_t)(v0 + row) * BATCH + b0 + col] = acc[m][n][r] * 0x1p-16f;
        }
}

// ---------------------------------------------------------------------------
// K3b (fallback only): cols 0..255 — these bytes ARE the E rows. Block =
// (tile, 64-row half): preload own E rows to regs, fence, compute, overwrite.
// Row-local aliasing only; other tiles/halves untouched. Runs after K3a.
// ---------------------------------------------------------------------------
__global__ __launch_bounds__(512, 1) void gemm2b_kernel(
    const u16* __restrict__ EgBase,   // == (u16*)out, RSTR=2048, TSTR=262144
    const u16* __restrict__ xsT, float* __restrict__ out)
{
    __shared__ char ldsB[32768];      // 256 rows x 128 B

    const int tid  = threadIdx.x;
    const int lane = tid & 63;
    const int wid  = tid >> 6;        // 8 waves: 2 (rows) x 4 (cols)
    const int wr = wid >> 2, wc = wid & 3;
    const int lr = lane & 15, lk = lane >> 4;

    const int bid  = xcd_swz(blockIdx.x, gridDim.x);
    const int tile = bid >> 1;
    const int h    = bid & 1;
    const u16* Et  = EgBase + (size_t)tile * 262144;

    // preload this half's E rows (64 x 512 u16) into regs
    f16x8 af[2][16];
    #pragma unroll
    for (int m = 0; m < 2; ++m) {
        const int row = h * 64 + wr * 32 + m * 16 + lr;
        #pragma unroll
        for (int kb = 0; kb < 16; ++kb)
            af[m][kb] = *reinterpret_cast<const f16x8*>(
                Et + (size_t)row * 2048 + kb * 32 + lk * 8);
    }
    asm volatile("s_waitcnt vmcnt(0)" ::: "memory");
    __syncthreads();   // all E reads complete before any out write below

    f32x4 acc[2][4] = {};
    for (int kt = 0; kt < 8; ++kt) {
        __syncthreads();
        {   // stage xsT rows 0..255 x 64 k  (32 KB)
            const int srow = tid >> 1;
            const int sp   = (tid & 1) * 4;
            const u16* g = xsT + (size_t)srow * TOPIC + kt * 64 + sp * 8;
            const int4* gv = reinterpret_cast<const int4*>(g);
            int4 a = gv[0], b = gv[1], cc = gv[2], d = gv[3];
            *reinterpret_cast<int4*>(ldsB + swz(srow, (sp + 0) * 16)) = a;
            *reinterpret_cast<int4*>(ldsB + swz(srow, (sp + 1) * 16)) = b;
            *reinterpret_cast<int4*>(ldsB + swz(srow, (sp + 2) * 16)) = cc;
            *reinterpret_cast<int4*>(ldsB + swz(srow, (sp + 3) * 16)) = d;
        }
        __syncthreads();
        #pragma unroll
        for (int kk = 0; kk < 2; ++kk) {
            f16x8 bf[4];
            #pragma unroll
            for (int n = 0; n < 4; ++n)
                bf[n] = *reinterpret_cast<const f16x8*>(ldsB + swz(wc * 64 + n * 16 + lr, kk * 64 + lk * 16));
            #pragma unroll
            for (int m = 0; m < 2; ++m)
                #pragma unroll
                for (int n = 0; n < 4; ++n)
                    acc[m][n] = __builtin_amdgcn_mfma_f32_16x16x32_f16(
                        af[m][kt * 2 + kk], bf[n], acc[m][n], 0, 0, 0);
        }
    }

    #pragma unroll
    for (int m = 0; m < 2; ++m)
      #pragma unroll
      for (int n = 0; n < 4; ++n)
        #pragma unroll
        for (int r = 0; r < 4; ++r) {
            const int row = h * 64 + wr * 32 + m * 16 + lk * 4 + r;
            const int col = wc * 64 + n * 16 + lr;
            out[((size_t)tile * 128 + row) * BATCH + col] = acc[m][n][r] * 0x1p-16f;
        }
}

// ---------------------------------------------------------------------------
extern "C" void kernel_launch(void* const* d_in, const int* in_sizes, int n_in,
                              void* d_out, int out_size, void* d_ws, size_t ws_size,
                              hipStream_t stream)
{
    const float* x     = (const float*)d_in[0];
    const float* beta0 = (const float*)d_in[1];
    const float* betat = (const float*)d_in[2];
    float* out = (float*)d_out;

    // ws: s[512] @0 | shared 1MB @4096 (betat16, later xsT) | optional E @4MB
    const size_t need_min = 4096 + (size_t)BATCH * TOPIC * 2;   // ~1.05 MB (proven available)
    if (ws_size < need_min) return;
    float* s_g  = (float*)d_ws;
    u16*   buf1 = (u16*)((char*)d_ws + 4096);

    const size_t E_OFF = 4u * 1024u * 1024u;
    const bool big = ws_size >= E_OFF + (size_t)VOC * TOPIC * 2;

    hipMemsetAsync(d_ws, 0, 2048, stream);                      // zero s
    cvt_betat_kernel<<<256, 256, 0, stream>>>(betat, buf1);     // buf1 = betat16

    if (big) {
        u16* EgW = (u16*)((char*)d_ws + E_OFF);
        gemm1_kernel<<<2000, 512, 0, stream>>>(beta0, buf1, EgW, (size_t)128 * 512, 512, s_g);
        xst_kernel<<<dim3(BATCH / 32, TOPIC / 32), dim3(32, 32), 0, stream>>>(x, s_g, buf1);
        gemm2a_kernel<<<4000, 512, 0, stream>>>(EgW, (size_t)128 * 512, 512, buf1, out, 0, 4);
    } else {
        // E[v][t] of tile i -> first 1024 B of out row v (row stride 4096 B)
        u16* EgO = (u16*)d_out;
        gemm1_kernel<<<2000, 512, 0, stream>>>(beta0, buf1, EgO, (size_t)262144, 2048, s_g);
        xst_kernel<<<dim3(BATCH / 32, TOPIC / 32), dim3(32, 32), 0, stream>>>(x, s_g, buf1);
        gemm2a_kernel<<<3000, 512, 0, stream>>>(EgO, (size_t)262144, 2048, buf1, out, 256, 3);
        gemm2b_kernel<<<2000, 512, 0, stream>>>(EgO, buf1, out);
    }
}

// Round 5
// 515.381 us; speedup vs baseline: 1.2870x; 1.1292x over previous
//
#include <hip/hip_runtime.h>

typedef _Float16 f16x8 __attribute__((ext_vector_type(8)));
typedef float    f32x4 __attribute__((ext_vector_type(4)));
typedef unsigned short u16;

#define VOC   128000
#define TOPIC 512
#define EMB   1024
#define BATCH 1024
#define ROWB  128   // LDS row = 64 f16 = 128 B

__device__ __forceinline__ int swz(int row, int kbyte) {
    return row * ROWB + (kbyte ^ ((row & 7) << 4));
}
__device__ __forceinline__ int xcd_swz(int bid, int nwg) {
    return (bid & 7) * (nwg >> 3) + (bid >> 3);
}
union H2U { _Float16 h; u16 u; };

#define SBAR() asm volatile("s_barrier" ::: "memory")
#define WVM0() asm volatile("s_waitcnt vmcnt(0)" ::: "memory")
#define WLG0() asm volatile("s_waitcnt lgkmcnt(0)" ::: "memory")

// ---------------------------------------------------------------------------
// K0: betat f32 -> f16 (into the ws MB that xst later overwrites with xsT)
// ---------------------------------------------------------------------------
__global__ void cvt_betat_kernel(const float* __restrict__ betat, u16* __restrict__ bt16) {
    const size_t g = (size_t)blockIdx.x * 256 + threadIdx.x;
    const float4* src = reinterpret_cast<const float4*>(betat) + g * 2;
    float4 a = src[0], b = src[1];
    f16x8 h;
    h[0]=(_Float16)a.x; h[1]=(_Float16)a.y; h[2]=(_Float16)a.z; h[3]=(_Float16)a.w;
    h[4]=(_Float16)b.x; h[5]=(_Float16)b.y; h[6]=(_Float16)b.z; h[7]=(_Float16)b.w;
    *(reinterpret_cast<f16x8*>(bt16) + g) = h;
}

// ---------------------------------------------------------------------------
// K1: W = beta0 @ betat16^T; E=f16(exp(W)); col-sums. 128x256 tile, BK=64.
// 2-phase dbuf pipeline, raw barriers + counted waits (T3 minimum recipe).
// ---------------------------------------------------------------------------
__global__ __launch_bounds__(512, 2) void gemm1_kernel(
    const float* __restrict__ beta0, const u16* __restrict__ bt16,
    u16* __restrict__ Eg, size_t TSTR, int RSTR, float* __restrict__ sg)
{
    __shared__ char lds[98304];   // A: 2x16KB @0, B: 2x32KB @32768

    const int tid  = threadIdx.x;
    const int lane = tid & 63;
    const int wid  = tid >> 6;            // 8 waves: 2 (v) x 4 (t)
    const int wr = wid >> 2, wc = wid & 3;
    const int lr = lane & 15, lk = lane >> 4;
    const int srow8  = lane >> 3;
    const int schunk = ((lane & 7) ^ srow8) * 8;

    const int bid  = xcd_swz(blockIdx.x, gridDim.x);
    const int t0   = (bid & 1) * 256;
    const int tile = bid >> 1;
    const int v0   = tile * 128;

    const int arow = tid >> 2;
    const int asp  = (tid & 3) * 2;

    f32x4 acc[4][4] = {};
    float4 rA[4];

    auto loadA = [&](int kt) {
        const float4* g = reinterpret_cast<const float4*>(
            beta0 + (size_t)(v0 + arow) * EMB + kt * 64 + asp * 8);
        rA[0] = g[0]; rA[1] = g[1]; rA[2] = g[2]; rA[3] = g[3];
    };
    auto issueB = [&](int kt, int buf) {
        const u16* bsrc = bt16 + (size_t)(t0 + wid * 8 + srow8) * EMB + kt * 64 + schunk;
        char* dstb = lds + 32768 + buf * 32768;
        #pragma unroll
        for (int p = 0; p < 4; ++p)
            __builtin_amdgcn_global_load_lds(
                (const __attribute__((address_space(1))) unsigned int*)(bsrc + (size_t)p * 64 * EMB),
                (__attribute__((address_space(3))) unsigned int*)(dstb + (p * 64 + wid * 8) * ROWB),
                16, 0, 0);
    };

    issueB(0, 0);
    loadA(0);

    for (int kt = 0; kt < EMB / 64; ++kt) {
        const int cur = kt & 1;
        char* ldsA = lds + cur * 16384;
        char* ldsB = lds + 32768 + cur * 32768;

        SBAR();   // all waves finished MFMA(kt-1) -> buf[cur^1] reusable
        WVM0();   // B(kt) landed in ldsB[cur]; A(kt) in regs (issued 1 phase ago)
        {
            f16x8 h;
            h[0]=(_Float16)rA[0].x; h[1]=(_Float16)rA[0].y; h[2]=(_Float16)rA[0].z; h[3]=(_Float16)rA[0].w;
            h[4]=(_Float16)rA[1].x; h[5]=(_Float16)rA[1].y; h[6]=(_Float16)rA[1].z; h[7]=(_Float16)rA[1].w;
            *reinterpret_cast<f16x8*>(ldsA + swz(arow, asp * 16)) = h;
            f16x8 h2;
            h2[0]=(_Float16)rA[2].x; h2[1]=(_Float16)rA[2].y; h2[2]=(_Float16)rA[2].z; h2[3]=(_Float16)rA[2].w;
            h2[4]=(_Float16)rA[3].x; h2[5]=(_Float16)rA[3].y; h2[6]=(_Float16)rA[3].z; h2[7]=(_Float16)rA[3].w;
            *reinterpret_cast<f16x8*>(ldsA + swz(arow, (asp + 1) * 16)) = h2;
        }
        if (kt + 1 < EMB / 64) { issueB(kt + 1, cur ^ 1); loadA(kt + 1); }
        WLG0();   // own ds_writes drained (cheap)
        SBAR();   // stage visible to all; kt+1 loads remain IN FLIGHT
        #pragma unroll
        for (int ks = 0; ks < 2; ++ks) {
            f16x8 af[4], bf[4];
            #pragma unroll
            for (int m = 0; m < 4; ++m)
                af[m] = *reinterpret_cast<const f16x8*>(ldsA + swz(wr * 64 + m * 16 + lr, ks * 64 + lk * 16));
            #pragma unroll
            for (int n = 0; n < 4; ++n)
                bf[n] = *reinterpret_cast<const f16x8*>(ldsB + swz(wc * 64 + n * 16 + lr, ks * 64 + lk * 16));
            #pragma unroll
            for (int m = 0; m < 4; ++m)
                #pragma unroll
                for (int n = 0; n < 4; ++n)
                    acc[m][n] = __builtin_amdgcn_mfma_f32_16x16x32_f16(
                        af[m], bf[n], acc[m][n], 0, 0, 0);
        }
    }

    // Epilogue (unchanged): exp -> LDS repack -> E write + col sums
    __syncthreads();
    u16* ldsE = reinterpret_cast<u16*>(lds);   // 64 x 264 u16
    float csum = 0.f;
    #pragma unroll
    for (int c = 0; c < 2; ++c) {
        if (wr == c) {
            #pragma unroll
            for (int m = 0; m < 4; ++m)
              #pragma unroll
              for (int n = 0; n < 4; ++n)
                #pragma unroll
                for (int r = 0; r < 4; ++r) {
                    const int row = m * 16 + lk * 4 + r;
                    const int col = wc * 64 + n * 16 + lr;
                    H2U cv; cv.h = (_Float16)__expf(acc[m][n][r]);
                    ldsE[row * 264 + col] = cv.u;
                }
        }
        __syncthreads();
        {
            const int row8 = tid >> 3, seg = tid & 7;
            const int4* srcp = reinterpret_cast<const int4*>(&ldsE[row8 * 264 + seg * 32]);
            u16* dst = Eg + tile * TSTR + (size_t)(c * 64 + row8) * RSTR + t0 + seg * 32;
            int4 v0v = srcp[0], v1v = srcp[1], v2v = srcp[2], v3v = srcp[3];
            int4* dp = reinterpret_cast<int4*>(dst);
            dp[0] = v0v; dp[1] = v1v; dp[2] = v2v; dp[3] = v3v;
        }
        if (tid < 256) {
            float s = 0.f;
            for (int r = 0; r < 64; ++r) { H2U cv; cv.u = ldsE[r * 264 + tid]; s += (float)cv.h; }
            csum += s;
        }
        __syncthreads();
    }
    if (tid < 256) atomicAdd(sg + t0 + tid, csum);
}

// ---------------------------------------------------------------------------
// K2: xsT[b][t] = f16( x[t][b] * 65536 / s[t] )
// ---------------------------------------------------------------------------
__global__ void xst_kernel(const float* __restrict__ x, const float* __restrict__ s,
                           u16* __restrict__ xsT)
{
    __shared__ float tile[32][33];
    const int b0 = blockIdx.x * 32, t0 = blockIdx.y * 32;
    const int tx = threadIdx.x, ty = threadIdx.y;
    tile[ty][tx] = x[(size_t)(t0 + ty) * BATCH + b0 + tx];
    __syncthreads();
    const float sc = 65536.0f / s[t0 + tx];
    H2U cv; cv.h = (_Float16)(tile[tx][ty] * sc);
    xsT[(size_t)(b0 + ty) * TOPIC + t0 + tx] = cv.u;
}

// ---------------------------------------------------------------------------
// K3a: out = (E @ xsT^T) * 2^-16 ; 128x256 tile; both operands gload_lds;
//      2-phase dbuf pipeline with raw barriers.
// ---------------------------------------------------------------------------
__global__ __launch_bounds__(512, 2) void gemm2a_kernel(
    const u16* __restrict__ Eg, size_t TSTR, int RSTR,
    const u16* __restrict__ xsT, float* __restrict__ out, int c0, int nch)
{
    __shared__ char lds[98304];   // A: 2x16KB @0, B: 2x32KB @32768

    const int tid  = threadIdx.x;
    const int lane = tid & 63;
    const int wid  = tid >> 6;
    const int wr = wid >> 2, wc = wid & 3;
    const int lr = lane & 15, lk = lane >> 4;
    const int srow8  = lane >> 3;
    const int schunk = ((lane & 7) ^ srow8) * 8;

    const int bid   = xcd_swz(blockIdx.x, gridDim.x);
    const int tile  = bid / nch;
    const int chunk = bid % nch;
    const int b0    = c0 + chunk * 256;
    const int v0    = tile * 128;
    const u16* Et   = Eg + tile * TSTR;

    f32x4 acc[4][4] = {};

    auto issueAB = [&](int kt, int buf) {
        const int k0 = kt * 64;
        char* dA = lds + buf * 16384;
        char* dB = lds + 32768 + buf * 32768;
        #pragma unroll
        for (int p = 0; p < 2; ++p) {
            const int rbase = p * 64 + wid * 8;
            __builtin_amdgcn_global_load_lds(
                (const __attribute__((address_space(1))) unsigned int*)
                    (Et + (size_t)(rbase + srow8) * RSTR + k0 + schunk),
                (__attribute__((address_space(3))) unsigned int*)(dA + rbase * ROWB),
                16, 0, 0);
        }
        #pragma unroll
        for (int p = 0; p < 4; ++p) {
            const int rbase = p * 64 + wid * 8;
            __builtin_amdgcn_global_load_lds(
                (const __attribute__((address_space(1))) unsigned int*)
                    (xsT + (size_t)(b0 + rbase + srow8) * TOPIC + k0 + schunk),
                (__attribute__((address_space(3))) unsigned int*)(dB + rbase * ROWB),
                16, 0, 0);
        }
    };

    issueAB(0, 0);

    for (int kt = 0; kt < TOPIC / 64; ++kt) {
        const int cur = kt & 1;
        char* ldsA = lds + cur * 16384;
        char* ldsB = lds + 32768 + cur * 32768;

        SBAR();                                 // MFMA(kt-1) done everywhere
        WVM0();                                 // own tile-kt loads landed
        if (kt + 1 < TOPIC / 64) issueAB(kt + 1, cur ^ 1);
        SBAR();                                 // all waves confirmed tile kt
        #pragma unroll
        for (int ks = 0; ks < 2; ++ks) {
            f16x8 af[4], bf[4];
            #pragma unroll
            for (int m = 0; m < 4; ++m)
                af[m] = *reinterpret_cast<const f16x8*>(ldsA + swz(wr * 64 + m * 16 + lr, ks * 64 + lk * 16));
            #pragma unroll
            for (int n = 0; n < 4; ++n)
                bf[n] = *reinterpret_cast<const f16x8*>(ldsB + swz(wc * 64 + n * 16 + lr, ks * 64 + lk * 16));
            #pragma unroll
            for (int m = 0; m < 4; ++m)
                #pragma unroll
                for (int n = 0; n < 4; ++n)
                    acc[m][n] = __builtin_amdgcn_mfma_f32_16x16x32_f16(
                        af[m], bf[n], acc[m][n], 0, 0, 0);
        }
    }

    #pragma unroll
    for (int m = 0; m < 4; ++m)
      #pragma unroll
      for (int n = 0; n < 4; ++n)
        #pragma unroll
        for (int r = 0; r < 4; ++r) {
            const int row = wr * 64 + m * 16 + lk * 4 + r;
            const int col = wc * 64 + n * 16 + lr;
            out[(size_t)(v0 + row) * BATCH + b0 + col] = acc[m][n][r] * 0x1p-16f;
        }
}

// ---------------------------------------------------------------------------
// K3b (fallback): cols 0..255 (these bytes ARE E). Preload own E to regs,
// fence, then 2-phase dbuf xsT staging.
// ---------------------------------------------------------------------------
__global__ __launch_bounds__(512, 2) void gemm2b_kernel(
    const u16* __restrict__ EgBase,   // == (u16*)out, RSTR=2048, TSTR=262144
    const u16* __restrict__ xsT, float* __restrict__ out)
{
    __shared__ char lds[65536];       // B dbuf: 2 x 32KB

    const int tid  = threadIdx.x;
    const int lane = tid & 63;
    const int wid  = tid >> 6;        // 8 waves: 2 (rows) x 4 (cols)
    const int wr = wid >> 2, wc = wid & 3;
    const int lr = lane & 15, lk = lane >> 4;

    const int bid  = xcd_swz(blockIdx.x, gridDim.x);
    const int tile = bid >> 1;
    const int h    = bid & 1;
    const u16* Et  = EgBase + (size_t)tile * 262144;

    // preload this half's E rows (64 x 512 u16) into regs
    f16x8 af[2][16];
    #pragma unroll
    for (int m = 0; m < 2; ++m) {
        const int row = h * 64 + wr * 32 + m * 16 + lr;
        #pragma unroll
        for (int kb = 0; kb < 16; ++kb)
            af[m][kb] = *reinterpret_cast<const f16x8*>(
                Et + (size_t)row * 2048 + kb * 32 + lk * 8);
    }
    WVM0();
    __syncthreads();   // all E reads complete before any out write below

    int4 rX[4];
    auto loadX = [&](int kt) {
        const int srow = tid >> 1;
        const int sp   = (tid & 1) * 4;
        const int4* gv = reinterpret_cast<const int4*>(
            xsT + (size_t)srow * TOPIC + kt * 64 + sp * 8);
        rX[0] = gv[0]; rX[1] = gv[1]; rX[2] = gv[2]; rX[3] = gv[3];
    };
    loadX(0);

    f32x4 acc[2][4] = {};
    for (int kt = 0; kt < 8; ++kt) {
        const int cur = kt & 1;
        char* ldsB = lds + cur * 32768;

        SBAR();
        WVM0();   // X(kt) regs ready (issued 1 phase ago)
        {
            const int srow = tid >> 1;
            const int sp   = (tid & 1) * 4;
            *reinterpret_cast<int4*>(ldsB + swz(srow, (sp + 0) * 16)) = rX[0];
            *reinterpret_cast<int4*>(ldsB + swz(srow, (sp + 1) * 16)) = rX[1];
            *reinterpret_cast<int4*>(ldsB + swz(srow, (sp + 2) * 16)) = rX[2];
            *reinterpret_cast<int4*>(ldsB + swz(srow, (sp + 3) * 16)) = rX[3];
        }
        if (kt + 1 < 8) loadX(kt + 1);
        WLG0();
        SBAR();
        #pragma unroll
        for (int kk = 0; kk < 2; ++kk) {
            f16x8 bf[4];
            #pragma unroll
            for (int n = 0; n < 4; ++n)
                bf[n] = *reinterpret_cast<const f16x8*>(ldsB + swz(wc * 64 + n * 16 + lr, kk * 64 + lk * 16));
            #pragma unroll
            for (int m = 0; m < 2; ++m)
                #pragma unroll
                for (int n = 0; n < 4; ++n)
                    acc[m][n] = __builtin_amdgcn_mfma_f32_16x16x32_f16(
                        af[m][kt * 2 + kk], bf[n], acc[m][n], 0, 0, 0);
        }
    }

    #pragma unroll
    for (int m = 0; m < 2; ++m)
      #pragma unroll
      for (int n = 0; n < 4; ++n)
        #pragma unroll
        for (int r = 0; r < 4; ++r) {
            const int row = h * 64 + wr * 32 + m * 16 + lk * 4 + r;
            const int col = wc * 64 + n * 16 + lr;
            out[((size_t)tile * 128 + row) * BATCH + col] = acc[m][n][r] * 0x1p-16f;
        }
}

// ---------------------------------------------------------------------------
extern "C" void kernel_launch(void* const* d_in, const int* in_sizes, int n_in,
                              void* d_out, int out_size, void* d_ws, size_t ws_size,
                              hipStream_t stream)
{
    const float* x     = (const float*)d_in[0];
    const float* beta0 = (const float*)d_in[1];
    const float* betat = (const float*)d_in[2];
    float* out = (float*)d_out;

    const size_t need_min = 4096 + (size_t)BATCH * TOPIC * 2;   // ~1.05 MB (proven)
    if (ws_size < need_min) return;
    float* s_g  = (float*)d_ws;
    u16*   buf1 = (u16*)((char*)d_ws + 4096);

    const size_t E_OFF = 4u * 1024u * 1024u;
    const bool big = ws_size >= E_OFF + (size_t)VOC * TOPIC * 2;

    hipMemsetAsync(d_ws, 0, 2048, stream);
    cvt_betat_kernel<<<256, 256, 0, stream>>>(betat, buf1);

    if (big) {
        u16* EgW = (u16*)((char*)d_ws + E_OFF);
        gemm1_kernel<<<2000, 512, 0, stream>>>(beta0, buf1, EgW, (size_t)128 * 512, 512, s_g);
        xst_kernel<<<dim3(BATCH / 32, TOPIC / 32), dim3(32, 32), 0, stream>>>(x, s_g, buf1);
        gemm2a_kernel<<<4000, 512, 0, stream>>>(EgW, (size_t)128 * 512, 512, buf1, out, 0, 4);
    } else {
        u16* EgO = (u16*)d_out;
        gemm1_kernel<<<2000, 512, 0, stream>>>(beta0, buf1, EgO, (size_t)262144, 2048, s_g);
        xst_kernel<<<dim3(BATCH / 32, TOPIC / 32), dim3(32, 32), 0, stream>>>(x, s_g, buf1);
        gemm2a_kernel<<<3000, 512, 0, stream>>>(EgO, (size_t)262144, 2048, buf1, out, 256, 3);
        gemm2b_kernel<<<2000, 512, 0, stream>>>(EgO, buf1, out);
    }
}